// Round 1
// baseline (3362.933 us; speedup 1.0000x reference)
//
#include <hip/hip_runtime.h>
#include <math.h>

#define T_ 12
#define N_ 20000
#define E_ 320000
#define FIN_ 128
#define H_ 256
#define G_ 256
#define C_ 10

// ---------------- workspace layout (bytes) ----------------
// zeroed region first: [deg | cnt | fill | emb]
static const size_t OFF_DEG   = 0;                  // T*N f32   (960000)
static const size_t OFF_CNT   = 960000;             // T*N i32   (960000)
static const size_t OFF_FILL  = 1920000;            // T*N i32   (960000)
static const size_t OFF_EMB   = 2880000;            // T*256 f32 (12288)
static const size_t ZERO_BYTES= 2892288;
static const size_t OFF_DINV  = 2892288;            // T*N f32   (960000)
static const size_t OFF_CP    = 3852288;            // T*(N+1) i32 (960048 -> pad 960256)
static const size_t OFF_EROW  = 4812544;            // T*E i32   (15360000)
static const size_t OFF_ENORM = 20172544;           // T*E f32   (15360000)
static const size_t OFF_HPRE  = 35532544;           // N*256 f32 (20480000)
static const size_t OFF_HCUR  = 56012544;           // N*256 f32 (20480000)
// total ~76.5 MB

// ---------------- CSR build ----------------
__global__ __launch_bounds__(256) void hist_kernel(const int* __restrict__ ei,
                                                   const float* __restrict__ ea,
                                                   float* __restrict__ deg,
                                                   int* __restrict__ cnt) {
  int idx = blockIdx.x * 256 + threadIdx.x;
  if (idx >= T_ * E_) return;
  int t = idx / E_;
  int e = idx - t * E_;
  int c = ei[t * 2 * E_ + E_ + e];
  float w = ea[t * E_ + e];
  atomicAdd(&deg[t * N_ + c], w);
  atomicAdd(&cnt[t * N_ + c], 1);
}

__global__ __launch_bounds__(1024) void scan_kernel(const int* __restrict__ cnt,
                                                    const float* __restrict__ deg,
                                                    int* __restrict__ colptr,
                                                    float* __restrict__ dinv) {
  const int t = blockIdx.x;
  __shared__ int s[1024];
  const int tid = threadIdx.x;
  int base = 0;
  for (int c0 = 0; c0 < N_; c0 += 1024) {
    int i = c0 + tid;
    int v = (i < N_) ? cnt[t * N_ + i] : 0;
    s[tid] = v;
    __syncthreads();
    for (int off = 1; off < 1024; off <<= 1) {
      int add = (tid >= off) ? s[tid - off] : 0;
      __syncthreads();
      s[tid] += add;
      __syncthreads();
    }
    if (i < N_) {
      colptr[t * (N_ + 1) + i] = base + s[tid] - v;  // exclusive
      dinv[t * N_ + i] = rsqrtf(deg[t * N_ + i] + 1.0f);
    }
    base += s[1023];
    __syncthreads();
  }
  if (tid == 0) colptr[t * (N_ + 1) + N_] = base;
}

__global__ __launch_bounds__(256) void fill_kernel(const int* __restrict__ ei,
                                                   const float* __restrict__ ea,
                                                   const int* __restrict__ colptr,
                                                   const float* __restrict__ dinv,
                                                   int* __restrict__ fill,
                                                   int* __restrict__ erow,
                                                   float* __restrict__ enorm) {
  int idx = blockIdx.x * 256 + threadIdx.x;
  if (idx >= T_ * E_) return;
  int t = idx / E_;
  int e = idx - t * E_;
  int r = ei[t * 2 * E_ + e];
  int c = ei[t * 2 * E_ + E_ + e];
  float w = ea[t * E_ + e];
  int pos = colptr[t * (N_ + 1) + c] + atomicAdd(&fill[t * N_ + c], 1);
  erow[t * E_ + pos] = r;
  enorm[t * E_ + pos] = dinv[t * N_ + r] * w * dinv[t * N_ + c];
}

// ---------------- fp32 GEMM: C[M,256] = A[M,K] @ B[K,256] ----------------
template <int K>
__global__ __launch_bounds__(256) void gemm_f32(const float* __restrict__ A,
                                                const float* __restrict__ B,
                                                float* __restrict__ C, int M) {
  __shared__ __align__(16) float As[16][68];
  __shared__ __align__(16) float Bs[16][68];
  const int bm = blockIdx.x * 64;
  const int bn = blockIdx.y * 64;
  const int tid = threadIdx.x;
  const int tx = tid & 15, ty = tid >> 4;
  const int am = tid >> 2, ak = (tid & 3) * 4;
  const int bk = tid >> 4, bn_ = (tid & 15) * 4;
  float acc[4][4] = {};
  for (int k0 = 0; k0 < K; k0 += 16) {
    float4 av = make_float4(0.f, 0.f, 0.f, 0.f);
    if (bm + am < M) av = *(const float4*)&A[(size_t)(bm + am) * K + k0 + ak];
    As[ak + 0][am] = av.x; As[ak + 1][am] = av.y;
    As[ak + 2][am] = av.z; As[ak + 3][am] = av.w;
    float4 bv = *(const float4*)&B[(size_t)(k0 + bk) * 256 + bn + bn_];
    *(float4*)&Bs[bk][bn_] = bv;
    __syncthreads();
#pragma unroll
    for (int kk = 0; kk < 16; ++kk) {
      float4 a4 = *(const float4*)&As[kk][ty * 4];
      float4 b4 = *(const float4*)&Bs[kk][tx * 4];
      float a[4] = {a4.x, a4.y, a4.z, a4.w};
      float b[4] = {b4.x, b4.y, b4.z, b4.w};
#pragma unroll
      for (int i = 0; i < 4; ++i)
#pragma unroll
        for (int j = 0; j < 4; ++j) acc[i][j] = fmaf(a[i], b[j], acc[i][j]);
    }
    __syncthreads();
  }
#pragma unroll
  for (int i = 0; i < 4; ++i) {
    int m = bm + ty * 4 + i;
    if (m < M)
      *(float4*)&C[(size_t)m * 256 + bn + tx * 4] =
          make_float4(acc[i][0], acc[i][1], acc[i][2], acc[i][3]);
  }
}

// ---------------- per-node gather aggregate + bias + relu ----------------
__global__ __launch_bounds__(256) void agg_kernel(const float* __restrict__ hpre,
                                                  float* __restrict__ hout,
                                                  const int* __restrict__ erow,
                                                  const float* __restrict__ enorm,
                                                  const int* __restrict__ colptr,
                                                  const float* __restrict__ dinv,
                                                  const float* __restrict__ bias) {
  const int node = blockIdx.x * 4 + (threadIdx.x >> 6);
  const int lane = threadIdx.x & 63;
  if (node >= N_) return;
  float4 acc = make_float4(0.f, 0.f, 0.f, 0.f);
  const int s0 = colptr[node], s1 = colptr[node + 1];
  for (int i = s0; i < s1; ++i) {
    const int r = erow[i];
    const float nm = enorm[i];
    const float4 hv = *(const float4*)&hpre[(size_t)r * 256 + lane * 4];
    acc.x = fmaf(nm, hv.x, acc.x);
    acc.y = fmaf(nm, hv.y, acc.y);
    acc.z = fmaf(nm, hv.z, acc.z);
    acc.w = fmaf(nm, hv.w, acc.w);
  }
  const float di = dinv[node];
  const float sw = di * di;
  const float4 hs = *(const float4*)&hpre[(size_t)node * 256 + lane * 4];
  const float4 bv = *(const float4*)&bias[lane * 4];
  acc.x = fmaxf(fmaf(sw, hs.x, acc.x) + bv.x, 0.f);
  acc.y = fmaxf(fmaf(sw, hs.y, acc.y) + bv.y, 0.f);
  acc.z = fmaxf(fmaf(sw, hs.z, acc.z) + bv.z, 0.f);
  acc.w = fmaxf(fmaf(sw, hs.w, acc.w) + bv.w, 0.f);
  *(float4*)&hout[(size_t)node * 256 + lane * 4] = acc;
}

// ---------------- mean pool over nodes -> emb[t] ----------------
__global__ __launch_bounds__(256) void mean_kernel(const float* __restrict__ h,
                                                   float* __restrict__ embp) {
  const int ch = threadIdx.x;
  float acc = 0.f;
  for (int n = blockIdx.x; n < N_; n += gridDim.x)
    acc += h[(size_t)n * 256 + ch];
  atomicAdd(&embp[ch], acc * (1.0f / N_));
}

// ---------------- GRU (12 steps) + final linear, one block ----------------
__global__ __launch_bounds__(768) void gru_kernel(const float* __restrict__ emb,
                                                  const float* __restrict__ Wih,
                                                  const float* __restrict__ Whh,
                                                  const float* __restrict__ bih,
                                                  const float* __restrict__ bhh,
                                                  const float* __restrict__ Wc,
                                                  const float* __restrict__ bc,
                                                  float* __restrict__ out) {
  __shared__ float sh[G_];
  __shared__ float xt[H_];
  __shared__ float gx[3 * G_];
  __shared__ float gh[3 * G_];
  const int tid = threadIdx.x;
  if (tid < G_) sh[tid] = 0.f;
  for (int t = 0; t < T_; ++t) {
    if (tid < H_) xt[tid] = emb[t * H_ + tid];
    __syncthreads();  // sh + xt stable; prev-iter gate reads of gx/gh done
    float ax = bih[tid];
    float ah = bhh[tid];
    const float4* wi = (const float4*)&Wih[(size_t)tid * H_];
    const float4* wh = (const float4*)&Whh[(size_t)tid * G_];
    const float4* x4 = (const float4*)xt;
    const float4* h4 = (const float4*)sh;
#pragma unroll 8
    for (int k = 0; k < H_ / 4; ++k) {
      float4 a = wi[k], bx = x4[k];
      ax += a.x * bx.x + a.y * bx.y + a.z * bx.z + a.w * bx.w;
      float4 c = wh[k], d = h4[k];
      ah += c.x * d.x + c.y * d.y + c.z * d.z + c.w * d.w;
    }
    gx[tid] = ax;
    gh[tid] = ah;
    __syncthreads();  // gx/gh ready; all matvec reads of sh done
    if (tid < G_) {
      float r = 1.f / (1.f + __expf(-(gx[tid] + gh[tid])));
      float z = 1.f / (1.f + __expf(-(gx[G_ + tid] + gh[G_ + tid])));
      float n = tanhf(gx[2 * G_ + tid] + r * gh[2 * G_ + tid]);
      sh[tid] = (1.f - z) * n + z * sh[tid];
    }
  }
  __syncthreads();
  const int wv = tid >> 6, lane = tid & 63;
  if (wv < C_) {
    float p = 0.f;
#pragma unroll
    for (int i = 0; i < 4; ++i) {
      int j = lane + 64 * i;
      p += sh[j] * Wc[(size_t)j * C_ + wv];
    }
    for (int off = 32; off > 0; off >>= 1) p += __shfl_down(p, off);
    if (lane == 0) out[wv] = p + bc[wv];
  }
}

extern "C" void kernel_launch(void* const* d_in, const int* in_sizes, int n_in,
                              void* d_out, int out_size, void* d_ws, size_t ws_size,
                              hipStream_t stream) {
  const float* x   = (const float*)d_in[0];
  const int*   ei  = (const int*)d_in[1];
  const float* ea  = (const float*)d_in[2];
  const float* W1  = (const float*)d_in[3];
  const float* b1  = (const float*)d_in[4];
  const float* W2  = (const float*)d_in[5];
  const float* b2  = (const float*)d_in[6];
  const float* Wih = (const float*)d_in[7];
  const float* Whh = (const float*)d_in[8];
  const float* bih = (const float*)d_in[9];
  const float* bhh = (const float*)d_in[10];
  const float* Wc  = (const float*)d_in[11];
  const float* bc  = (const float*)d_in[12];
  float* out = (float*)d_out;

  char* w = (char*)d_ws;
  float* deg   = (float*)(w + OFF_DEG);
  int*   cnt   = (int*)(w + OFF_CNT);
  int*   fill  = (int*)(w + OFF_FILL);
  float* emb   = (float*)(w + OFF_EMB);
  float* dinv  = (float*)(w + OFF_DINV);
  int*   cp    = (int*)(w + OFF_CP);
  int*   erow  = (int*)(w + OFF_EROW);
  float* enorm = (float*)(w + OFF_ENORM);
  float* hpre  = (float*)(w + OFF_HPRE);
  float* hcur  = (float*)(w + OFF_HCUR);

  hipMemsetAsync(d_ws, 0, ZERO_BYTES, stream);

  const int teb = (T_ * E_ + 255) / 256;
  hist_kernel<<<teb, 256, 0, stream>>>(ei, ea, deg, cnt);
  scan_kernel<<<T_, 1024, 0, stream>>>(cnt, deg, cp, dinv);
  fill_kernel<<<teb, 256, 0, stream>>>(ei, ea, cp, dinv, fill, erow, enorm);

  dim3 gemm_grid((N_ + 63) / 64, 4);
  for (int t = 0; t < T_; ++t) {
    gemm_f32<FIN_><<<gemm_grid, 256, 0, stream>>>(x + (size_t)t * N_ * FIN_, W1, hpre, N_);
    agg_kernel<<<N_ / 4, 256, 0, stream>>>(hpre, hcur, erow + (size_t)t * E_,
                                           enorm + (size_t)t * E_, cp + (size_t)t * (N_ + 1),
                                           dinv + (size_t)t * N_, b1);
    gemm_f32<H_><<<gemm_grid, 256, 0, stream>>>(hcur, W2, hpre, N_);
    agg_kernel<<<N_ / 4, 256, 0, stream>>>(hpre, hcur, erow + (size_t)t * E_,
                                           enorm + (size_t)t * E_, cp + (size_t)t * (N_ + 1),
                                           dinv + (size_t)t * N_, b2);
    mean_kernel<<<256, 256, 0, stream>>>(hcur, emb + t * H_);
  }
  gru_kernel<<<1, 768, 0, stream>>>(emb, Wih, Whh, bih, bhh, Wc, bc, out);
}

// Round 2
// 2514.890 us; speedup vs baseline: 1.3372x; 1.3372x over previous
//
#include <hip/hip_runtime.h>
#include <math.h>

#define T_ 12
#define N_ 20000
#define E_ 320000
#define FIN_ 128
#define H_ 256
#define G_ 256
#define C_ 10

typedef __attribute__((ext_vector_type(8))) short bf16x8;
typedef __attribute__((ext_vector_type(4))) float f32x4;

// ---------------- workspace layout (bytes) ----------------
static const size_t OFF_DEG   = 0;         // T*N f32
static const size_t OFF_CNT   = 960000;    // T*N i32
static const size_t OFF_FILL  = 1920000;   // T*N i32
static const size_t OFF_EMB   = 2880000;   // T*256 f32
static const size_t ZERO_BYTES= 2892288;
static const size_t OFF_DINV  = 2892288;   // T*N f32
static const size_t OFF_CP    = 3852288;   // T*(N+1) i32 (padded)
static const size_t OFF_EROW  = 4812544;   // T*E i32
static const size_t OFF_ENORM = 20172544;  // T*E f32
static const size_t OFF_W1BT  = 35532544;  // 256x128 bf16
static const size_t OFF_W2BT  = 35598080;  // 256x256 bf16
static const size_t OFF_WIHT  = 35729152;  // 256x768 f32
static const size_t OFF_WHHT  = 36515584;  // 256x768 f32
static const size_t OFF_GX    = 37302016;  // 12x768 f32
static const size_t OFF_XBT   = 37338880;  // N*128 bf16 (per-t, reused)
static const size_t OFF_P     = 42458880;  // N*256 bf16
static const size_t OFF_Q     = 52698880;  // N*256 bf16
// end ~62.9 MB

__device__ __forceinline__ float bf2f(unsigned short u) {
  return __uint_as_float(((unsigned int)u) << 16);
}
__device__ __forceinline__ unsigned short f2bf(float f) {
  unsigned int u = __float_as_uint(f);
  unsigned int r = (u + 0x7FFFu + ((u >> 16) & 1u)) >> 16;  // RNE
  return (unsigned short)r;
}
__device__ __forceinline__ float bflo(unsigned int u) { return __uint_as_float(u << 16); }
__device__ __forceinline__ float bfhi(unsigned int u) { return __uint_as_float(u & 0xFFFF0000u); }
__device__ __forceinline__ unsigned int packbf(float lo, float hi) {
  return (unsigned int)f2bf(lo) | ((unsigned int)f2bf(hi) << 16);
}

// ---------------- CSR build ----------------
__global__ __launch_bounds__(256) void hist_kernel(const int* __restrict__ ei,
                                                   const float* __restrict__ ea,
                                                   float* __restrict__ deg,
                                                   int* __restrict__ cnt) {
  int idx = blockIdx.x * 256 + threadIdx.x;
  if (idx >= T_ * E_) return;
  int t = idx / E_;
  int e = idx - t * E_;
  int c = ei[t * 2 * E_ + E_ + e];
  float w = ea[t * E_ + e];
  atomicAdd(&deg[t * N_ + c], w);
  atomicAdd(&cnt[t * N_ + c], 1);
}

__global__ __launch_bounds__(1024) void scan_kernel(const int* __restrict__ cnt,
                                                    const float* __restrict__ deg,
                                                    int* __restrict__ colptr,
                                                    float* __restrict__ dinv) {
  const int t = blockIdx.x;
  __shared__ int s[1024];
  const int tid = threadIdx.x;
  int base = 0;
  for (int c0 = 0; c0 < N_; c0 += 1024) {
    int i = c0 + tid;
    int v = (i < N_) ? cnt[t * N_ + i] : 0;
    s[tid] = v;
    __syncthreads();
    for (int off = 1; off < 1024; off <<= 1) {
      int add = (tid >= off) ? s[tid - off] : 0;
      __syncthreads();
      s[tid] += add;
      __syncthreads();
    }
    if (i < N_) {
      colptr[t * (N_ + 1) + i] = base + s[tid] - v;
      dinv[t * N_ + i] = rsqrtf(deg[t * N_ + i] + 1.0f);
    }
    base += s[1023];
    __syncthreads();
  }
  if (tid == 0) colptr[t * (N_ + 1) + N_] = base;
}

__global__ __launch_bounds__(256) void fill_kernel(const int* __restrict__ ei,
                                                   const float* __restrict__ ea,
                                                   const int* __restrict__ colptr,
                                                   const float* __restrict__ dinv,
                                                   int* __restrict__ fill,
                                                   int* __restrict__ erow,
                                                   float* __restrict__ enorm) {
  int idx = blockIdx.x * 256 + threadIdx.x;
  if (idx >= T_ * E_) return;
  int t = idx / E_;
  int e = idx - t * E_;
  int r = ei[t * 2 * E_ + e];
  int c = ei[t * 2 * E_ + E_ + e];
  float w = ea[t * E_ + e];
  int pos = colptr[t * (N_ + 1) + c] + atomicAdd(&fill[t * N_ + c], 1);
  erow[t * E_ + pos] = r;
  enorm[t * E_ + pos] = dinv[t * N_ + r] * w * dinv[t * N_ + c];
}

// ---------------- weight prep: bf16 B^T for GEMMs, f32 transpose for GRU ----------------
__global__ __launch_bounds__(256) void prep_kernel(const float* __restrict__ W1,
                                                   const float* __restrict__ W2,
                                                   const float* __restrict__ Wih,
                                                   const float* __restrict__ Whh,
                                                   unsigned short* __restrict__ W1bT,
                                                   unsigned short* __restrict__ W2bT,
                                                   float* __restrict__ WihT,
                                                   float* __restrict__ WhhT) {
  int idx = blockIdx.x * 256 + threadIdx.x;
  if (idx < 32768) {                       // W1bT[n*128+k] = bf(W1[k*256+n])
    int n = idx >> 7, k = idx & 127;
    W1bT[idx] = f2bf(W1[k * 256 + n]);
  } else if (idx < 98304) {                // W2bT[n*256+k] = bf(W2[k*256+n])
    int j = idx - 32768;
    int n = j >> 8, k = j & 255;
    W2bT[j] = f2bf(W2[k * 256 + n]);
  } else if (idx < 294912) {               // WihT[k*768+c] = Wih[c*256+k]
    int j = idx - 98304;
    int k = j / 768, c = j - k * 768;
    WihT[j] = Wih[c * 256 + k];
  } else if (idx < 491520) {               // WhhT[k*768+c] = Whh[c*256+k]
    int j = idx - 294912;
    int k = j / 768, c = j - k * 768;
    WhhT[j] = Whh[c * 256 + k];
  }
}

// ---------------- cast x_t fp32 -> bf16 ----------------
__global__ __launch_bounds__(256) void castx_kernel(const float* __restrict__ x,
                                                    unsigned short* __restrict__ xb) {
  int idx = blockIdx.x * 256 + threadIdx.x;  // one float4 per thread
  float4 v = ((const float4*)x)[idx];
  ushort4 o;
  o.x = f2bf(v.x); o.y = f2bf(v.y); o.z = f2bf(v.z); o.w = f2bf(v.w);
  ((ushort4*)xb)[idx] = o;
}

// ---------------- gather aggregate (bf16 in/out, fp32 accum), incl self-loop ----------------
__global__ __launch_bounds__(256) void agg128(const unsigned short* __restrict__ h,
                                              unsigned short* __restrict__ o,
                                              const int* __restrict__ erow,
                                              const float* __restrict__ enorm,
                                              const int* __restrict__ cp,
                                              const float* __restrict__ dinv) {
  const int node = blockIdx.x * 4 + (threadIdx.x >> 6);
  const int lane = threadIdx.x & 63;
  float a0 = 0.f, a1 = 0.f;
  const int s0 = cp[node], s1 = cp[node + 1];
  for (int i = s0; i < s1; ++i) {
    const int r = erow[i];
    const float nm = enorm[i];
    unsigned int u = *(const unsigned int*)&h[(size_t)r * 128 + lane * 2];
    a0 = fmaf(nm, bflo(u), a0);
    a1 = fmaf(nm, bfhi(u), a1);
  }
  const float di = dinv[node];
  const float sw = di * di;
  unsigned int us = *(const unsigned int*)&h[(size_t)node * 128 + lane * 2];
  a0 = fmaf(sw, bflo(us), a0);
  a1 = fmaf(sw, bfhi(us), a1);
  *(unsigned int*)&o[(size_t)node * 128 + lane * 2] = packbf(a0, a1);
}

__global__ __launch_bounds__(256) void agg256(const unsigned short* __restrict__ h,
                                              unsigned short* __restrict__ o,
                                              const int* __restrict__ erow,
                                              const float* __restrict__ enorm,
                                              const int* __restrict__ cp,
                                              const float* __restrict__ dinv) {
  const int node = blockIdx.x * 4 + (threadIdx.x >> 6);
  const int lane = threadIdx.x & 63;
  float a0 = 0.f, a1 = 0.f, a2 = 0.f, a3 = 0.f;
  const int s0 = cp[node], s1 = cp[node + 1];
  for (int i = s0; i < s1; ++i) {
    const int r = erow[i];
    const float nm = enorm[i];
    uint2 u = *(const uint2*)&h[(size_t)r * 256 + lane * 4];
    a0 = fmaf(nm, bflo(u.x), a0);
    a1 = fmaf(nm, bfhi(u.x), a1);
    a2 = fmaf(nm, bflo(u.y), a2);
    a3 = fmaf(nm, bfhi(u.y), a3);
  }
  const float di = dinv[node];
  const float sw = di * di;
  uint2 us = *(const uint2*)&h[(size_t)node * 256 + lane * 4];
  a0 = fmaf(sw, bflo(us.x), a0);
  a1 = fmaf(sw, bfhi(us.x), a1);
  a2 = fmaf(sw, bflo(us.y), a2);
  a3 = fmaf(sw, bfhi(us.y), a3);
  uint2 ov;
  ov.x = packbf(a0, a1);
  ov.y = packbf(a2, a3);
  *(uint2*)&o[(size_t)node * 256 + lane * 4] = ov;
}

// ---------------- bf16 MFMA GEMM: C[M,256] = relu(A[M,K] @ BT^T + bias) ----------------
template <int K>
__global__ __launch_bounds__(256) void gemm_bf16(const unsigned short* __restrict__ A,
                                                 const unsigned short* __restrict__ BT,  // [256][K]
                                                 const float* __restrict__ bias,
                                                 unsigned short* __restrict__ C, int M) {
  const int tid = threadIdx.x;
  const int w = tid >> 6;          // wave -> n-block of 64
  const int l = tid & 63;
  const int l16 = l & 15, lk = l >> 4;  // A/B fragment: row/col = l16, k-base = lk*8
  const int bm = blockIdx.x * 64;
  const int colbase = w * 64;
  f32x4 acc[4][4] = {};  // [m-frag][n-frag]
  for (int ks = 0; ks < K; ks += 32) {
    bf16x8 a[4], b[4];
#pragma unroll
    for (int f = 0; f < 4; ++f) {
      int row = bm + f * 16 + l16;
      if (row >= M) row = M - 1;  // clamp; garbage rows discarded at store
      a[f] = *(const bf16x8*)&A[(size_t)row * K + ks + lk * 8];
      int col = colbase + f * 16 + l16;
      b[f] = *(const bf16x8*)&BT[(size_t)col * K + ks + lk * 8];
    }
#pragma unroll
    for (int m = 0; m < 4; ++m)
#pragma unroll
      for (int n = 0; n < 4; ++n)
        acc[m][n] = __builtin_amdgcn_mfma_f32_16x16x32_bf16(a[m], b[n], acc[m][n], 0, 0, 0);
  }
#pragma unroll
  for (int n = 0; n < 4; ++n) {
    int col = colbase + n * 16 + l16;
    float bv = bias[col];
#pragma unroll
    for (int m = 0; m < 4; ++m) {
#pragma unroll
      for (int r = 0; r < 4; ++r) {
        int row = bm + m * 16 + lk * 4 + r;  // C/D: col=lane&15, row=(lane>>4)*4+reg
        if (row < M) {
          float v = fmaxf(acc[m][n][r] + bv, 0.f);
          C[(size_t)row * 256 + col] = f2bf(v);
        }
      }
    }
  }
}

// ---------------- mean pool (bf16 in) ----------------
__global__ __launch_bounds__(256) void mean_bf16(const unsigned short* __restrict__ h,
                                                 float* __restrict__ embp) {
  const int ch = threadIdx.x;
  float acc = 0.f;
  for (int n = blockIdx.x; n < N_; n += gridDim.x)
    acc += bf2f(h[(size_t)n * 256 + ch]);
  atomicAdd(&embp[ch], acc * (1.0f / N_));
}

// ---------------- GX[t] = Wih @ emb_t + bih, all t in parallel ----------------
__global__ __launch_bounds__(768) void gx_kernel(const float* __restrict__ emb,
                                                 const float* __restrict__ WihT,  // [256][768]
                                                 const float* __restrict__ bih,
                                                 float* __restrict__ GX) {
  const int t = blockIdx.x;
  const int tid = threadIdx.x;
  __shared__ float se[256];
  if (tid < 256) se[tid] = emb[t * 256 + tid];
  __syncthreads();
  float p0 = 0.f, p1 = 0.f, p2 = 0.f, p3 = 0.f;
#pragma unroll 8
  for (int k = 0; k < 256; k += 4) {
    p0 = fmaf(WihT[(size_t)(k + 0) * 768 + tid], se[k + 0], p0);
    p1 = fmaf(WihT[(size_t)(k + 1) * 768 + tid], se[k + 1], p1);
    p2 = fmaf(WihT[(size_t)(k + 2) * 768 + tid], se[k + 2], p2);
    p3 = fmaf(WihT[(size_t)(k + 3) * 768 + tid], se[k + 3], p3);
  }
  GX[t * 768 + tid] = (p0 + p1) + (p2 + p3) + bih[tid];
}

// ---------------- sequential GRU (coalesced WhhT) + final linear ----------------
__global__ __launch_bounds__(768) void gru2_kernel(const float* __restrict__ GX,
                                                   const float* __restrict__ WhhT,  // [256][768]
                                                   const float* __restrict__ bhh,
                                                   const float* __restrict__ Wc,
                                                   const float* __restrict__ bc,
                                                   float* __restrict__ out) {
  __shared__ float sh[256];
  __shared__ float sgh[768];
  const int tid = threadIdx.x;
  if (tid < 256) sh[tid] = 0.f;
  __syncthreads();
  for (int t = 0; t < T_; ++t) {
    float p0 = 0.f, p1 = 0.f, p2 = 0.f, p3 = 0.f;
#pragma unroll 8
    for (int k = 0; k < 256; k += 4) {
      p0 = fmaf(WhhT[(size_t)(k + 0) * 768 + tid], sh[k + 0], p0);
      p1 = fmaf(WhhT[(size_t)(k + 1) * 768 + tid], sh[k + 1], p1);
      p2 = fmaf(WhhT[(size_t)(k + 2) * 768 + tid], sh[k + 2], p2);
      p3 = fmaf(WhhT[(size_t)(k + 3) * 768 + tid], sh[k + 3], p3);
    }
    sgh[tid] = (p0 + p1) + (p2 + p3) + bhh[tid];
    __syncthreads();
    if (tid < 256) {
      const float* gx = &GX[t * 768];
      float r = 1.f / (1.f + __expf(-(gx[tid] + sgh[tid])));
      float z = 1.f / (1.f + __expf(-(gx[256 + tid] + sgh[256 + tid])));
      float n = tanhf(gx[512 + tid] + r * sgh[512 + tid]);
      sh[tid] = (1.f - z) * n + z * sh[tid];
    }
    __syncthreads();
  }
  const int wv = tid >> 6, lane = tid & 63;
  if (wv < C_) {
    float p = 0.f;
#pragma unroll
    for (int i = 0; i < 4; ++i) {
      int j = lane + 64 * i;
      p += sh[j] * Wc[(size_t)j * C_ + wv];
    }
    for (int off = 32; off > 0; off >>= 1) p += __shfl_down(p, off);
    if (lane == 0) out[wv] = p + bc[wv];
  }
}

extern "C" void kernel_launch(void* const* d_in, const int* in_sizes, int n_in,
                              void* d_out, int out_size, void* d_ws, size_t ws_size,
                              hipStream_t stream) {
  const float* x   = (const float*)d_in[0];
  const int*   ei  = (const int*)d_in[1];
  const float* ea  = (const float*)d_in[2];
  const float* W1  = (const float*)d_in[3];
  const float* b1  = (const float*)d_in[4];
  const float* W2  = (const float*)d_in[5];
  const float* b2  = (const float*)d_in[6];
  const float* Wih = (const float*)d_in[7];
  const float* Whh = (const float*)d_in[8];
  const float* bih = (const float*)d_in[9];
  const float* bhh = (const float*)d_in[10];
  const float* Wc  = (const float*)d_in[11];
  const float* bc  = (const float*)d_in[12];
  float* out = (float*)d_out;

  char* w = (char*)d_ws;
  float* deg   = (float*)(w + OFF_DEG);
  int*   cnt   = (int*)(w + OFF_CNT);
  int*   fill  = (int*)(w + OFF_FILL);
  float* emb   = (float*)(w + OFF_EMB);
  float* dinv  = (float*)(w + OFF_DINV);
  int*   cp    = (int*)(w + OFF_CP);
  int*   erow  = (int*)(w + OFF_EROW);
  float* enorm = (float*)(w + OFF_ENORM);
  unsigned short* W1bT = (unsigned short*)(w + OFF_W1BT);
  unsigned short* W2bT = (unsigned short*)(w + OFF_W2BT);
  float* WihT  = (float*)(w + OFF_WIHT);
  float* WhhT  = (float*)(w + OFF_WHHT);
  float* GX    = (float*)(w + OFF_GX);
  unsigned short* xbt = (unsigned short*)(w + OFF_XBT);
  unsigned short* P   = (unsigned short*)(w + OFF_P);
  unsigned short* Q   = (unsigned short*)(w + OFF_Q);

  hipMemsetAsync(d_ws, 0, ZERO_BYTES, stream);

  prep_kernel<<<1920, 256, 0, stream>>>(W1, W2, Wih, Whh, W1bT, W2bT, WihT, WhhT);

  const int teb = (T_ * E_ + 255) / 256;
  hist_kernel<<<teb, 256, 0, stream>>>(ei, ea, deg, cnt);
  scan_kernel<<<T_, 1024, 0, stream>>>(cnt, deg, cp, dinv);
  fill_kernel<<<teb, 256, 0, stream>>>(ei, ea, cp, dinv, fill, erow, enorm);

  const int gemm_blocks = (N_ + 63) / 64;
  for (int t = 0; t < T_; ++t) {
    const int* cpt = cp + (size_t)t * (N_ + 1);
    const int* ert = erow + (size_t)t * E_;
    const float* ent = enorm + (size_t)t * E_;
    const float* dvt = dinv + (size_t)t * N_;
    castx_kernel<<<2500, 256, 0, stream>>>(x + (size_t)t * N_ * FIN_, xbt);
    agg128<<<N_ / 4, 256, 0, stream>>>(xbt, P, ert, ent, cpt, dvt);
    gemm_bf16<FIN_><<<gemm_blocks, 256, 0, stream>>>(P, W1bT, b1, Q, N_);
    agg256<<<N_ / 4, 256, 0, stream>>>(Q, P, ert, ent, cpt, dvt);
    gemm_bf16<H_><<<gemm_blocks, 256, 0, stream>>>(P, W2bT, b2, Q, N_);
    mean_bf16<<<256, 256, 0, stream>>>(Q, emb + t * H_);
  }
  gx_kernel<<<T_, 768, 0, stream>>>(emb, WihT, bih, GX);
  gru2_kernel<<<1, 768, 0, stream>>>(GX, WhhT, bhh, Wc, bc, out);
}